// Round 8
// baseline (132.478 us; speedup 1.0000x reference)
//
#include <hip/hip_runtime.h>
#include <hip/hip_bf16.h>

#define BB  4
#define LL  256
#define DD  256
#define HH  8
#define DHH 32
#define BL  1024   // B*L

typedef __attribute__((ext_vector_type(4))) float f32x4;

// ---------------------------------------------------------------------------
// Fused QKV projection + mask dtype detection.
// Blocks 0..127: 8 rows each of qu = Xq/sqrt(DH)+u, qv = Xq/sqrt(DH)+v, K, V.
//   (8 rows/block halves redundant Wq/Wk/Wv panel traffic vs 4 rows.)
// Block 128: mask dtype auto-detect (bool may arrive as u8/int32/f32);
//   flags[0] = 1 if elements are 4-byte, 0 if 1-byte.
// ---------------------------------------------------------------------------
__global__ __launch_bounds__(256) void qkv_kernel(
    const float* __restrict__ X,
    const float* __restrict__ Wq, const float* __restrict__ bq,
    const float* __restrict__ Wk, const float* __restrict__ bk,
    const float* __restrict__ Wv, const float* __restrict__ bv,
    const float* __restrict__ u,  const float* __restrict__ vp,
    const unsigned int* __restrict__ mask_w,
    float* __restrict__ qu, float* __restrict__ qv,
    float* __restrict__ K,  float* __restrict__ V,
    unsigned int* __restrict__ flags) {
  const int t = threadIdx.x;
  if (blockIdx.x == 128) {
    __shared__ int sf32, shib;
    if (t == 0) { sf32 = 0; shib = 0; }
    __syncthreads();
    int f = 0, hb = 0;
    for (int i = t; i < 16384; i += 256) {
      unsigned int x = mask_w[i];
      if (x == 0x3F800000u) f = 1;
      else if (x & 0xFFFFFF00u) hb = 1;
    }
    if (f)  atomicOr(&sf32, 1);
    if (hb) atomicOr(&shib, 1);
    __syncthreads();
    if (t == 0) flags[0] = (sf32 || !shib) ? 1u : 0u;
    return;
  }
  const int row0 = blockIdx.x * 8;
  const int c = t;
  float accq[8], acck[8], accv[8];
#pragma unroll
  for (int r = 0; r < 8; ++r) { accq[r] = 0.f; acck[r] = 0.f; accv[r] = 0.f; }
  const float4* Wq4 = (const float4*)(Wq + c * DD);
  const float4* Wk4 = (const float4*)(Wk + c * DD);
  const float4* Wv4 = (const float4*)(Wv + c * DD);
  const float4* X4  = (const float4*)X;
  const int xbase = row0 * (DD / 4);
#pragma unroll 4
  for (int j4 = 0; j4 < DD / 4; ++j4) {
    const float4 wq = Wq4[j4], wk = Wk4[j4], wv = Wv4[j4];
#pragma unroll
    for (int r = 0; r < 8; ++r) {
      const float4 x = X4[xbase + r * (DD / 4) + j4];
      accq[r] += x.x * wq.x + x.y * wq.y + x.z * wq.z + x.w * wq.w;
      acck[r] += x.x * wk.x + x.y * wk.y + x.z * wk.z + x.w * wk.w;
      accv[r] += x.x * wv.x + x.y * wv.y + x.z * wv.z + x.w * wv.w;
    }
  }
  const float scale = 0.17677669529663687f;  // 1/sqrt(32)
  const float uc = u[c], vc = vp[c], bqc = bq[c], bkc = bk[c], bvc = bv[c];
#pragma unroll
  for (int r = 0; r < 8; ++r) {
    const int idx = (row0 + r) * DD + c;
    const float pq = (accq[r] + bqc) * scale;
    qu[idx] = pq + uc;
    qv[idx] = pq + vc;
    K[idx]  = acck[r] + bkc;
    V[idx]  = accv[r] + bvc;
  }
}

// ---------------------------------------------------------------------------
// Main attention kernel (+ fused output projection).
// One block per (b, q-PAIR); 512 threads = 8 waves.
//
// rel (256 MiB, touch-once) is read with non-temporal loads; attn_out (8 MB,
// touch-once) uses nt stores. K/V/qu/qv/Wo keep normal (allocating) loads —
// they are the reused, cacheable working set.
//
// XCD-aware decode of blockIdx (MI355X dispatches block i -> XCD i%8):
//   x = blk&7 (XCD), j = blk>>3; b = x>>1, qpair = (x&1)*64 + j.
// => XCD pair {2b,2b+1} serves ALL q's of batch b; that XCD's L2 holds only
// K[b]+V[b] (512 KB << 4 MB), so K/V re-reads are L2 hits.
//
// Phase 1: wave w owns k-rows [32w, 32w+32). Lane l reads float4 l of each
//   row (coalesced 1KB/instr); lane's float4 is in head l>>3, so
//   shfl_xor(1,2,4) over the 8-lane group yields score[h][k]. One K-row
//   load feeds both q's; each q has its own rel row.
// Phase 2: 16 (q,h) pairs over 8 waves, softmax via 64-lane shfl tree.
// Phase 3: wave w re-walks its k-rows; one V-row load serves both q's;
//   cross-wave LDS reduce leaves ctx rows in LDS.
// Phase 4 (fused outproj): thread t computes out[b,q0+(t>>8), t&255] =
//   ctx_row . Wo[t&255,:] + bo — Wo row loads are L2-resident and overlap
//   other blocks' HBM streaming; removes the separate outproj kernel.
// ---------------------------------------------------------------------------
__global__ __launch_bounds__(512, 4) void attn_kernel(
    const float* __restrict__ qu, const float* __restrict__ qv,
    const float* __restrict__ Km, const float* __restrict__ Vm,
    const float* __restrict__ rel, const void* __restrict__ mask_raw,
    const unsigned int* __restrict__ flags,
    const float* __restrict__ Wo, const float* __restrict__ bo,
    float* __restrict__ attn_out, float* __restrict__ out) {
  const int blk = blockIdx.x;          // [0, 512)
  const int xcd = blk & 7;
  const int b = xcd >> 1;
  const int q0 = ((xcd & 1) * 64 + (blk >> 3)) * 2;
  const int t = threadIdx.x;
  const int wave = t >> 6, lane = t & 63;
  __shared__ float qu_s[2][DD], qv_s[2][DD];
  __shared__ float msk_s[2][LL];
  __shared__ float sc[2][HH][LL + 4];    // +4 pad: 8 head-writers -> 8 banks
  __shared__ float pctx[2][HH][DD + 4];  // per-wave partial ctx
  __shared__ float ctx_s[2][DD];

  {
    const int qq = t >> 8, d = t & 255;
    const int bq = b * LL + q0 + qq;
    qu_s[qq][d] = qu[bq * DD + d];
    qv_s[qq][d] = qv[bq * DD + d];
    bool masked;
    if (flags[0]) masked = ((const unsigned int*)mask_raw)[bq * LL + d] != 0u;
    else          masked = ((const unsigned char*)mask_raw)[bq * LL + d] != 0;
    msk_s[qq][d] = masked ? 1.f : 0.f;
  }
  __syncthreads();

  // ---- Phase 1: scores ----
  const float4 u40 = ((const float4*)qu_s[0])[lane];
  const float4 u41 = ((const float4*)qu_s[1])[lane];
  const float4 w40 = ((const float4*)qv_s[0])[lane];
  const float4 w41 = ((const float4*)qv_s[1])[lane];
  const int hol = lane >> 3;
  const int k0 = wave * 32;
  const float4* K4  = (const float4*)(Km + (size_t)b * LL * DD) +
                      (size_t)k0 * 64 + lane;
  const f32x4* R40 = (const f32x4*)rel +
                     (size_t)(b * LL + q0) * (LL * 64) + (size_t)k0 * 64 + lane;
  const f32x4* R41 = R40 + (size_t)LL * 64;
#pragma unroll 4
  for (int i = 0; i < 32; ++i) {
    const int k = k0 + i;
    const float4 kk = K4[(size_t)i * 64];
    const f32x4 r0 = __builtin_nontemporal_load(R40 + (size_t)i * 64);
    const f32x4 r1 = __builtin_nontemporal_load(R41 + (size_t)i * 64);
    float s0 = u40.x * kk.x + u40.y * kk.y + u40.z * kk.z + u40.w * kk.w
             + w40.x * r0.x + w40.y * r0.y + w40.z * r0.z + w40.w * r0.w;
    float s1 = u41.x * kk.x + u41.y * kk.y + u41.z * kk.z + u41.w * kk.w
             + w41.x * r1.x + w41.y * r1.y + w41.z * r1.z + w41.w * r1.w;
    s0 += __shfl_xor(s0, 1); s0 += __shfl_xor(s0, 2); s0 += __shfl_xor(s0, 4);
    s1 += __shfl_xor(s1, 1); s1 += __shfl_xor(s1, 2); s1 += __shfl_xor(s1, 4);
    if ((lane & 7) == 0) {
      sc[0][hol][k] = (msk_s[0][k] != 0.f) ? -1e18f : s0;
      sc[1][hol][k] = (msk_s[1][k] != 0.f) ? -1e18f : s1;
    }
  }
  __syncthreads();

  // ---- Phase 2: softmax over 16 (q,h) pairs, 2 per wave ----
#pragma unroll
  for (int pp = 0; pp < 2; ++pp) {
    const int pair = wave + pp * 8;
    const int qq = pair >> 3, h = pair & 7;
    float v0 = sc[qq][h][lane], v1 = sc[qq][h][lane + 64];
    float v2 = sc[qq][h][lane + 128], v3 = sc[qq][h][lane + 192];
    float m = fmaxf(fmaxf(v0, v1), fmaxf(v2, v3));
#pragma unroll
    for (int off = 32; off >= 1; off >>= 1) m = fmaxf(m, __shfl_xor(m, off));
    float e0 = __expf(v0 - m), e1 = __expf(v1 - m);
    float e2 = __expf(v2 - m), e3 = __expf(v3 - m);
    float s = (e0 + e1) + (e2 + e3);
#pragma unroll
    for (int off = 32; off >= 1; off >>= 1) s += __shfl_xor(s, off);
    const float inv = 1.0f / s;
    e0 *= inv; e1 *= inv; e2 *= inv; e3 *= inv;
    sc[qq][h][lane] = e0; sc[qq][h][lane + 64] = e1;
    sc[qq][h][lane + 128] = e2; sc[qq][h][lane + 192] = e3;
    float* aout = attn_out + (((size_t)(b * HH + h) * LL + (q0 + qq)) * LL);
    __builtin_nontemporal_store(e0, aout + lane);
    __builtin_nontemporal_store(e1, aout + lane + 64);
    __builtin_nontemporal_store(e2, aout + lane + 128);
    __builtin_nontemporal_store(e3, aout + lane + 192);
  }
  __syncthreads();

  // ---- Phase 3: ctx partials; one V-row load serves both q's ----
  {
    const float4* V4 = (const float4*)(Vm + (size_t)b * LL * DD) +
                       (size_t)k0 * 64 + lane;
    float4 a0 = make_float4(0.f, 0.f, 0.f, 0.f);
    float4 a1 = make_float4(0.f, 0.f, 0.f, 0.f);
#pragma unroll 4
    for (int i = 0; i < 32; ++i) {
      const int k = k0 + i;
      const float p0 = sc[0][hol][k];
      const float p1 = sc[1][hol][k];
      const float4 vv = V4[(size_t)i * 64];
      a0.x += p0 * vv.x; a0.y += p0 * vv.y; a0.z += p0 * vv.z; a0.w += p0 * vv.w;
      a1.x += p1 * vv.x; a1.y += p1 * vv.y; a1.z += p1 * vv.z; a1.w += p1 * vv.w;
    }
    ((float4*)&pctx[0][wave][0])[lane] = a0;
    ((float4*)&pctx[1][wave][0])[lane] = a1;
  }
  __syncthreads();

  {
    const int qq = t >> 8, d = t & 255;
    float s = 0.f;
#pragma unroll
    for (int w = 0; w < HH; ++w) s += pctx[qq][w][d];
    ctx_s[qq][d] = s;
  }
  __syncthreads();

  // ---- Phase 4: fused output projection ----
  {
    const int qq = t >> 8, d = t & 255;
    const float4* W4 = (const float4*)(Wo + d * DD);
    const float4* C4 = (const float4*)ctx_s[qq];
    float acc = 0.f;
#pragma unroll 8
    for (int j4 = 0; j4 < DD / 4; ++j4) {
      const float4 w = W4[j4];
      const float4 c = C4[j4];
      acc += c.x * w.x + c.y * w.y + c.z * w.z + c.w * w.w;
    }
    out[(size_t)(b * LL + q0 + qq) * DD + d] = acc + bo[d];
  }
}

extern "C" void kernel_launch(void* const* d_in, const int* in_sizes, int n_in,
                              void* d_out, int out_size, void* d_ws, size_t ws_size,
                              hipStream_t stream) {
  (void)in_sizes; (void)n_in; (void)out_size; (void)ws_size;
  const float* X   = (const float*)d_in[0];
  const void*  msk = d_in[1];
  const float* rel = (const float*)d_in[2];
  const float* Wq  = (const float*)d_in[3];
  const float* bq  = (const float*)d_in[4];
  const float* Wk  = (const float*)d_in[5];
  const float* bk  = (const float*)d_in[6];
  const float* Wv  = (const float*)d_in[7];
  const float* bv  = (const float*)d_in[8];
  const float* Wo  = (const float*)d_in[9];
  const float* bo  = (const float*)d_in[10];
  const float* u   = (const float*)d_in[11];
  const float* vp  = (const float*)d_in[12];

  float* out  = (float*)d_out;
  float* attn = out + BL * DD;  // outputs: [out (B,L,D) | attn (B,H,L,L)]

  float* ws_f = (float*)d_ws;
  float* qu  = ws_f;
  float* qv  = qu + BL * DD;
  float* K   = qv + BL * DD;
  float* V   = K  + BL * DD;
  unsigned int* flags = (unsigned int*)(V + BL * DD);

  qkv_kernel<<<129, 256, 0, stream>>>(X, Wq, bq, Wk, bk, Wv, bv, u, vp,
                                      (const unsigned int*)msk,
                                      qu, qv, K, V, flags);
  attn_kernel<<<BL / 2, 512, 0, stream>>>(qu, qv, K, V, rel, msk, flags,
                                          Wo, bo, attn, out);
}

// Round 9
// 97.486 us; speedup vs baseline: 1.3589x; 1.3589x over previous
//
#include <hip/hip_runtime.h>
#include <hip/hip_bf16.h>

#define BB  4
#define LL  256
#define DD  256
#define HH  8
#define DHH 32
#define BL  1024   // B*L

typedef __attribute__((ext_vector_type(4))) float f32x4;

// ---------------------------------------------------------------------------
// Fused QKV projection + mask dtype detection.
// Blocks 0..255: qu = Xq/sqrt(DH)+u, qv = Xq/sqrt(DH)+v, K, V (4 rows each).
// Block 256: mask dtype auto-detect (bool may arrive as u8/int32/f32);
//   flags[0] = 1 if elements are 4-byte, 0 if 1-byte.
// (R8 lesson: 4 rows x 257 blocks keeps all CUs busy; 8-row variant used
//  only 129 blocks = half the GPU and regressed.)
// ---------------------------------------------------------------------------
__global__ __launch_bounds__(256) void qkv_kernel(
    const float* __restrict__ X,
    const float* __restrict__ Wq, const float* __restrict__ bq,
    const float* __restrict__ Wk, const float* __restrict__ bk,
    const float* __restrict__ Wv, const float* __restrict__ bv,
    const float* __restrict__ u,  const float* __restrict__ vp,
    const unsigned int* __restrict__ mask_w,
    float* __restrict__ qu, float* __restrict__ qv,
    float* __restrict__ K,  float* __restrict__ V,
    unsigned int* __restrict__ flags) {
  const int t = threadIdx.x;
  if (blockIdx.x == 256) {
    __shared__ int sf32, shib;
    if (t == 0) { sf32 = 0; shib = 0; }
    __syncthreads();
    int f = 0, hb = 0;
    for (int i = t; i < 16384; i += 256) {
      unsigned int x = mask_w[i];
      if (x == 0x3F800000u) f = 1;
      else if (x & 0xFFFFFF00u) hb = 1;
    }
    if (f)  atomicOr(&sf32, 1);
    if (hb) atomicOr(&shib, 1);
    __syncthreads();
    if (t == 0) flags[0] = (sf32 || !shib) ? 1u : 0u;
    return;
  }
  const int row0 = blockIdx.x * 4;
  const int c = t;
  float accq[4] = {0.f, 0.f, 0.f, 0.f};
  float acck[4] = {0.f, 0.f, 0.f, 0.f};
  float accv[4] = {0.f, 0.f, 0.f, 0.f};
  const float4* Wq4 = (const float4*)(Wq + c * DD);
  const float4* Wk4 = (const float4*)(Wk + c * DD);
  const float4* Wv4 = (const float4*)(Wv + c * DD);
  const float4* X4  = (const float4*)X;
  const int xbase = row0 * (DD / 4);
#pragma unroll 8
  for (int j4 = 0; j4 < DD / 4; ++j4) {
    const float4 wq = Wq4[j4], wk = Wk4[j4], wv = Wv4[j4];
#pragma unroll
    for (int r = 0; r < 4; ++r) {
      const float4 x = X4[xbase + r * (DD / 4) + j4];
      accq[r] += x.x * wq.x + x.y * wq.y + x.z * wq.z + x.w * wq.w;
      acck[r] += x.x * wk.x + x.y * wk.y + x.z * wk.z + x.w * wk.w;
      accv[r] += x.x * wv.x + x.y * wv.y + x.z * wv.z + x.w * wv.w;
    }
  }
  const float scale = 0.17677669529663687f;  // 1/sqrt(32)
  const float uc = u[c], vc = vp[c], bqc = bq[c], bkc = bk[c], bvc = bv[c];
#pragma unroll
  for (int r = 0; r < 4; ++r) {
    const int idx = (row0 + r) * DD + c;
    const float pq = (accq[r] + bqc) * scale;
    qu[idx] = pq + uc;
    qv[idx] = pq + vc;
    K[idx]  = acck[r] + bkc;
    V[idx]  = accv[r] + bvc;
  }
}

// ---------------------------------------------------------------------------
// Main attention kernel. One block per (b, q-PAIR); 512 threads = 8 waves.
//
// rel (256 MiB, touch-once) is read with non-temporal loads; attn_out (8 MB,
// touch-once) uses nt stores. K/V/qu/qv keep normal (allocating) loads —
// they are the reused, cacheable working set.
//
// XCD-aware decode of blockIdx (MI355X dispatches block i -> XCD i%8):
//   x = blk&7 (XCD), j = blk>>3; b = x>>1, qpair = (x&1)*64 + j.
// => XCD pair {2b,2b+1} serves ALL q's of batch b; that XCD's L2 holds only
// K[b]+V[b] (512 KB << 4 MB), so K/V re-reads are L2 hits.
//
// Phase 1: wave w owns k-rows [32w, 32w+32). Lane l reads float4 l of each
//   row (coalesced 1KB/instr); lane's float4 is in head l>>3, so
//   shfl_xor(1,2,4) over the 8-lane group yields score[h][k]. One K-row
//   load feeds both q's; each q has its own rel row.
// Phase 2: 16 (q,h) pairs over 8 waves, softmax via 64-lane shfl tree.
// Phase 3: wave w re-walks its k-rows; one V-row load serves both q's.
// ---------------------------------------------------------------------------
__global__ __launch_bounds__(512, 4) void attn_kernel(
    const float* __restrict__ qu, const float* __restrict__ qv,
    const float* __restrict__ Km, const float* __restrict__ Vm,
    const float* __restrict__ rel, const void* __restrict__ mask_raw,
    const unsigned int* __restrict__ flags,
    float* __restrict__ attn_out, float* __restrict__ ctx) {
  const int blk = blockIdx.x;          // [0, 512)
  const int xcd = blk & 7;
  const int b = xcd >> 1;
  const int q0 = ((xcd & 1) * 64 + (blk >> 3)) * 2;
  const int t = threadIdx.x;
  const int wave = t >> 6, lane = t & 63;
  __shared__ float qu_s[2][DD], qv_s[2][DD];
  __shared__ float msk_s[2][LL];
  __shared__ float sc[2][HH][LL + 4];    // +4 pad: 8 head-writers -> 8 banks
  __shared__ float pctx[2][HH][DD + 4];  // per-wave partial ctx

  {
    const int qq = t >> 8, d = t & 255;
    const int bq = b * LL + q0 + qq;
    qu_s[qq][d] = qu[bq * DD + d];
    qv_s[qq][d] = qv[bq * DD + d];
    bool masked;
    if (flags[0]) masked = ((const unsigned int*)mask_raw)[bq * LL + d] != 0u;
    else          masked = ((const unsigned char*)mask_raw)[bq * LL + d] != 0;
    msk_s[qq][d] = masked ? 1.f : 0.f;
  }
  __syncthreads();

  // ---- Phase 1: scores ----
  const float4 u40 = ((const float4*)qu_s[0])[lane];
  const float4 u41 = ((const float4*)qu_s[1])[lane];
  const float4 w40 = ((const float4*)qv_s[0])[lane];
  const float4 w41 = ((const float4*)qv_s[1])[lane];
  const int hol = lane >> 3;
  const int k0 = wave * 32;
  const float4* K4  = (const float4*)(Km + (size_t)b * LL * DD) +
                      (size_t)k0 * 64 + lane;
  const f32x4* R40 = (const f32x4*)rel +
                     (size_t)(b * LL + q0) * (LL * 64) + (size_t)k0 * 64 + lane;
  const f32x4* R41 = R40 + (size_t)LL * 64;
#pragma unroll 4
  for (int i = 0; i < 32; ++i) {
    const int k = k0 + i;
    const float4 kk = K4[(size_t)i * 64];
    const f32x4 r0 = __builtin_nontemporal_load(R40 + (size_t)i * 64);
    const f32x4 r1 = __builtin_nontemporal_load(R41 + (size_t)i * 64);
    float s0 = u40.x * kk.x + u40.y * kk.y + u40.z * kk.z + u40.w * kk.w
             + w40.x * r0.x + w40.y * r0.y + w40.z * r0.z + w40.w * r0.w;
    float s1 = u41.x * kk.x + u41.y * kk.y + u41.z * kk.z + u41.w * kk.w
             + w41.x * r1.x + w41.y * r1.y + w41.z * r1.z + w41.w * r1.w;
    s0 += __shfl_xor(s0, 1); s0 += __shfl_xor(s0, 2); s0 += __shfl_xor(s0, 4);
    s1 += __shfl_xor(s1, 1); s1 += __shfl_xor(s1, 2); s1 += __shfl_xor(s1, 4);
    if ((lane & 7) == 0) {
      sc[0][hol][k] = (msk_s[0][k] != 0.f) ? -1e18f : s0;
      sc[1][hol][k] = (msk_s[1][k] != 0.f) ? -1e18f : s1;
    }
  }
  __syncthreads();

  // ---- Phase 2: softmax over 16 (q,h) pairs, 2 per wave ----
#pragma unroll
  for (int pp = 0; pp < 2; ++pp) {
    const int pair = wave + pp * 8;
    const int qq = pair >> 3, h = pair & 7;
    float v0 = sc[qq][h][lane], v1 = sc[qq][h][lane + 64];
    float v2 = sc[qq][h][lane + 128], v3 = sc[qq][h][lane + 192];
    float m = fmaxf(fmaxf(v0, v1), fmaxf(v2, v3));
#pragma unroll
    for (int off = 32; off >= 1; off >>= 1) m = fmaxf(m, __shfl_xor(m, off));
    float e0 = __expf(v0 - m), e1 = __expf(v1 - m);
    float e2 = __expf(v2 - m), e3 = __expf(v3 - m);
    float s = (e0 + e1) + (e2 + e3);
#pragma unroll
    for (int off = 32; off >= 1; off >>= 1) s += __shfl_xor(s, off);
    const float inv = 1.0f / s;
    e0 *= inv; e1 *= inv; e2 *= inv; e3 *= inv;
    sc[qq][h][lane] = e0; sc[qq][h][lane + 64] = e1;
    sc[qq][h][lane + 128] = e2; sc[qq][h][lane + 192] = e3;
    float* aout = attn_out + (((size_t)(b * HH + h) * LL + (q0 + qq)) * LL);
    __builtin_nontemporal_store(e0, aout + lane);
    __builtin_nontemporal_store(e1, aout + lane + 64);
    __builtin_nontemporal_store(e2, aout + lane + 128);
    __builtin_nontemporal_store(e3, aout + lane + 192);
  }
  __syncthreads();

  // ---- Phase 3: ctx partials; one V-row load serves both q's ----
  {
    const float4* V4 = (const float4*)(Vm + (size_t)b * LL * DD) +
                       (size_t)k0 * 64 + lane;
    float4 a0 = make_float4(0.f, 0.f, 0.f, 0.f);
    float4 a1 = make_float4(0.f, 0.f, 0.f, 0.f);
#pragma unroll 4
    for (int i = 0; i < 32; ++i) {
      const int k = k0 + i;
      const float p0 = sc[0][hol][k];
      const float p1 = sc[1][hol][k];
      const float4 vv = V4[(size_t)i * 64];
      a0.x += p0 * vv.x; a0.y += p0 * vv.y; a0.z += p0 * vv.z; a0.w += p0 * vv.w;
      a1.x += p1 * vv.x; a1.y += p1 * vv.y; a1.z += p1 * vv.z; a1.w += p1 * vv.w;
    }
    ((float4*)&pctx[0][wave][0])[lane] = a0;
    ((float4*)&pctx[1][wave][0])[lane] = a1;
  }
  __syncthreads();

  {
    const int qq = t >> 8, d = t & 255;
    float s = 0.f;
#pragma unroll
    for (int w = 0; w < HH; ++w) s += pctx[qq][w][d];
    ctx[(size_t)(b * LL + q0 + qq) * DD + d] = s;
  }
}

// ---------------------------------------------------------------------------
// Output projection: out = ctx @ Wo.T + bo
// (Kept as a separate kernel: R8 showed fusing it into attn serializes its
//  uncoalesced Wo reads behind each block's barriers; standalone, the 256
//  blocks overlap each other and the cost stays hidden.)
// ---------------------------------------------------------------------------
__global__ __launch_bounds__(256) void outproj_kernel(
    const float* __restrict__ ctx, const float* __restrict__ Wo,
    const float* __restrict__ bo, float* __restrict__ out) {
  const int row0 = blockIdx.x * 4;
  const int c = threadIdx.x;
  float acc[4] = {0.f, 0.f, 0.f, 0.f};
  const float4* W4 = (const float4*)(Wo + c * DD);
  const float4* X4 = (const float4*)ctx;
  const int xbase = row0 * (DD / 4);
#pragma unroll 8
  for (int j4 = 0; j4 < DD / 4; ++j4) {
    const float4 w = W4[j4];
#pragma unroll
    for (int r = 0; r < 4; ++r) {
      const float4 x = X4[xbase + r * (DD / 4) + j4];
      acc[r] += x.x * w.x + x.y * w.y + x.z * w.z + x.w * w.w;
    }
  }
  const float boc = bo[c];
#pragma unroll
  for (int r = 0; r < 4; ++r) out[(row0 + r) * DD + c] = acc[r] + boc;
}

extern "C" void kernel_launch(void* const* d_in, const int* in_sizes, int n_in,
                              void* d_out, int out_size, void* d_ws, size_t ws_size,
                              hipStream_t stream) {
  (void)in_sizes; (void)n_in; (void)out_size; (void)ws_size;
  const float* X   = (const float*)d_in[0];
  const void*  msk = d_in[1];
  const float* rel = (const float*)d_in[2];
  const float* Wq  = (const float*)d_in[3];
  const float* bq  = (const float*)d_in[4];
  const float* Wk  = (const float*)d_in[5];
  const float* bk  = (const float*)d_in[6];
  const float* Wv  = (const float*)d_in[7];
  const float* bv  = (const float*)d_in[8];
  const float* Wo  = (const float*)d_in[9];
  const float* bo  = (const float*)d_in[10];
  const float* u   = (const float*)d_in[11];
  const float* vp  = (const float*)d_in[12];

  float* out  = (float*)d_out;
  float* attn = out + BL * DD;  // outputs: [out (B,L,D) | attn (B,H,L,L)]

  float* ws_f = (float*)d_ws;
  float* qu  = ws_f;
  float* qv  = qu + BL * DD;
  float* K   = qv + BL * DD;
  float* V   = K  + BL * DD;
  float* ctx = V  + BL * DD;
  unsigned int* flags = (unsigned int*)(ctx + BL * DD);

  qkv_kernel<<<257, 256, 0, stream>>>(X, Wq, bq, Wk, bk, Wv, bv, u, vp,
                                      (const unsigned int*)msk,
                                      qu, qv, K, V, flags);
  attn_kernel<<<BL / 2, 512, 0, stream>>>(qu, qv, K, V, rel, msk, flags,
                                          attn, ctx);
  outproj_kernel<<<BL / 4, 256, 0, stream>>>(ctx, Wo, bo, out);
}